// Round 16
// baseline (43.386 us; speedup 1.0000x reference)
//
#include <hip/hip_runtime.h>
#include <hip/hip_bf16.h>

#define B_  256
#define T_  256
#define C_  384
#define HS_ 64
#define BT_ (B_*T_)

typedef __attribute__((ext_vector_type(8))) short short8;
typedef __attribute__((ext_vector_type(4))) float f32x4;

// ---------- helpers ----------
__device__ __forceinline__ unsigned short f2bf(float f) {
    unsigned u = __float_as_uint(f);
    u += 0x7FFFu + ((u >> 16) & 1u);   // round-to-nearest-even
    return (unsigned short)(u >> 16);
}
// 2^x via v_exp_f32 (gfx950 hardware exp is base-2)
__device__ __forceinline__ float exp2_hw(float x) {
    return __builtin_amdgcn_exp2f(x);
}

// Raw barrier that does NOT drain vmcnt (unlike __syncthreads): LDS ordering
// via lgkmcnt(0); sched_barrier pins the fence (guide rule #18 / m201 template).
__device__ __forceinline__ void lds_barrier() {
    asm volatile("s_waitcnt lgkmcnt(0)" ::: "memory");
    __builtin_amdgcn_s_barrier();
    __builtin_amdgcn_sched_barrier(0);
}

// ---------- kernel 0: W -> MFMA-fragment-ordered bf16 ----------
// Wfrag[s][wn][f][lane] (short8): element col n = wn*48+f*16+(lane&15),
// k = s*32+(lane>>4)*8+j.
// Q columns pre-scaled by 384^-0.5 * log2(e)  (softmax runs in exp2 domain).
__global__ __launch_bounds__(256) void prep_wfrag(
    const float* __restrict__ Wq, const float* __restrict__ Wk,
    const float* __restrict__ Wv, unsigned short* __restrict__ Wfrag)
{
    const int tid  = blockIdx.x * 256 + threadIdx.x;   // 9216 threads
    const int lane = tid & 63;
    const int q    = tid >> 6;
    const int f    = q % 3;
    const int q2   = q / 3;
    const int wn   = q2 & 3;
    const int s    = q2 >> 2;

    const int n     = wn * 48 + f * 16 + (lane & 15);
    const int kbase = s * 32 + (lane >> 4) * 8;
    const float* src = (n < 64) ? Wq : (n < 128) ? Wk : Wv;
    const int c      = n & 63;
    const float scale = (n < 64) ? 0.07362222f : 1.0f;   // 384^-0.5 * log2(e)

    short8 out;
    #pragma unroll
    for (int j = 0; j < 8; ++j)
        out[j] = (short)f2bf(src[(size_t)(kbase + j) * HS_ + c] * scale);
    *(short8*)&Wfrag[(size_t)tid * 8] = out;
}

// ---------- fused kernel: QKV projection + causal flash attention ----------
// One block per batch, 1024 thr = 16 waves (4 waves/SIMD).
// GEMM: M=256 x N=192 x K=384; wave (wm,wn) owns rows wm*64..+64, cols wn*48..+48.
// X staged depth-2 with NON-TEMPORAL loads (X is stream-once; keeps W L1-hot).
// W fragments from L2/L1 (fragment-ordered). Raw s_barrier per step (no vmcnt
// drain -> prefetches stay in flight across barriers).
// Attention (swapped-MFMA): QK^T = mfma(K,Q); in-lane exp2-domain softmax +
// defer-max (T13); P -> PV B-frag in registers via cvt_pk + permlane (T12);
// PV = mfma(V,P) -> O^T; non-temporal output stores.
// LDS map (u16 units):
//   Qs  [256][72]  @ 0       (18432)
//   Ks  [256][72]  @ 18432   (18432)
//   Vts [64][264]  @ 36864   (16896)   V transposed: [h][tok]
//   Xs  [2][256][40] @ 53760 (20480)   GEMM staging (dead in phase 2)
// total 74240 u16 = 148480 B
#define LQ_OFF 0
#define LK_OFF 18432
#define LV_OFF 36864
#define LX_OFF 53760

__global__ __launch_bounds__(1024, 4) void head_fused(
    const float* __restrict__ X, const unsigned short* __restrict__ Wfrag,
    float* __restrict__ out)
{
    __shared__ unsigned short lds[74240];
    const int t    = threadIdx.x;
    const int w    = t >> 6;        // 0..15
    const int lane = t & 63;
    const int lo   = lane & 15;
    const int hi   = lane >> 4;
    const int b    = blockIdx.x;
    const int wm   = w >> 2, wn = w & 3;

    const float* Xb = X + (size_t)b * T_ * C_;
    const short8* Wf = (const short8*)Wfrag;

    // ================= phase 1: QKV GEMM =================
    const int srow  = t >> 2;       // 0..255
    const int squad = t & 3;        // 8-float chunk of the 32-k slice

    auto stage_load = [&](int k0, f32x4* g) {       // nt: bypass L1 (stream-once)
        const f32x4* p = (const f32x4*)(Xb + (size_t)srow * C_ + k0 + squad * 8);
        g[0] = __builtin_nontemporal_load(p);
        g[1] = __builtin_nontemporal_load(p + 1);
    };
    auto stage_write = [&](int buf, const f32x4* g) {
        unsigned a0, a1, a2, a3;
        asm("v_cvt_pk_bf16_f32 %0, %1, %2" : "=v"(a0) : "v"(g[0][0]), "v"(g[0][1]));
        asm("v_cvt_pk_bf16_f32 %0, %1, %2" : "=v"(a1) : "v"(g[0][2]), "v"(g[0][3]));
        asm("v_cvt_pk_bf16_f32 %0, %1, %2" : "=v"(a2) : "v"(g[1][0]), "v"(g[1][1]));
        asm("v_cvt_pk_bf16_f32 %0, %1, %2" : "=v"(a3) : "v"(g[1][2]), "v"(g[1][3]));
        uint4 p = { a0, a1, a2, a3 };
        *(uint4*)&lds[LX_OFF + buf * 10240 + srow * 40 + squad * 8] = p;
    };
    auto load_w = [&](int s, short8* wf) {      // coalesced fragment loads (L1-hot)
        const short8* base = Wf + ((size_t)(s * 4 + wn) * 3) * 64 + lane;
        #pragma unroll
        for (int f = 0; f < 3; ++f)
            wf[f] = base[f * 64];
    };

    f32x4  gx[2][2];                 // depth-2 X pipeline
    short8 wfr[2][3];
    stage_load(0, gx[0]);
    load_w(0, wfr[0]);
    stage_load(32, gx[1]);
    stage_write(0, gx[0]);
    lds_barrier();

    f32x4 acc[4][3];
    #pragma unroll
    for (int m = 0; m < 4; ++m)
        #pragma unroll
        for (int f = 0; f < 3; ++f)
            acc[m][f] = (f32x4){0.f, 0.f, 0.f, 0.f};

    #pragma unroll 2
    for (int s = 0; s < 12; ++s) {
        const int cur = s & 1;
        if (s < 10) stage_load((s + 2) * 32, gx[cur]);     // issue 2 ahead
        if (s < 11) load_w(s + 1, wfr[cur ^ 1]);           // W 1 ahead
        if (s < 11) stage_write(cur ^ 1, gx[cur ^ 1]);     // write s+1 (arrived)

        short8 af[4];                               // A-frag: row=lo, k=hi*8+j
        #pragma unroll
        for (int m = 0; m < 4; ++m)
            af[m] = *(const short8*)&lds[LX_OFF + cur * 10240 + (wm * 64 + m * 16 + lo) * 40 + hi * 8];
        #pragma unroll
        for (int m = 0; m < 4; ++m)
            #pragma unroll
            for (int f = 0; f < 3; ++f)
                acc[m][f] = __builtin_amdgcn_mfma_f32_16x16x32_bf16(af[m], wfr[cur][f], acc[m][f], 0, 0, 0);
        lds_barrier();
    }

    // epilogue: D col = wn*48+f*16+lo, row = wm*64+m*16+hi*4+r  -> LDS Q/K/Vt
    #pragma unroll
    for (int m = 0; m < 4; ++m) {
        const int rowb = wm * 64 + m * 16 + hi * 4;
        #pragma unroll
        for (int f = 0; f < 3; ++f) {
            const int base = wn * 48 + f * 16;      // frag fully inside one of Q/K/V
            if (base < 64) {
                #pragma unroll
                for (int r = 0; r < 4; ++r)
                    lds[LQ_OFF + (rowb + r) * 72 + base + lo] = f2bf(acc[m][f][r]);
            } else if (base < 128) {
                #pragma unroll
                for (int r = 0; r < 4; ++r)
                    lds[LK_OFF + (rowb + r) * 72 + (base - 64) + lo] = f2bf(acc[m][f][r]);
            } else {
                unsigned e0, e1;
                asm("v_cvt_pk_bf16_f32 %0, %1, %2" : "=v"(e0) : "v"(acc[m][f][0]), "v"(acc[m][f][1]));
                asm("v_cvt_pk_bf16_f32 %0, %1, %2" : "=v"(e1) : "v"(acc[m][f][2]), "v"(acc[m][f][3]));
                uint2 pk = { e0, e1 };
                *(uint2*)&lds[LV_OFF + (base - 128 + lo) * 264 + rowb] = pk;
            }
        }
    }
    lds_barrier();

    // ======== phase 2: causal flash attention (swapped MFMA, reg-only P) ========
    // Scores are in log2 domain (log2e folded into Q): p = exp2(s - M).
    // SIMD-balanced tile assignment: SIMD g gets {g, 15-g, 4+g, 11-g} = 18 steps
    const int sg  = w & 3, pos = w >> 2;
    const int tq  = (pos == 0) ? sg : (pos == 1) ? 15 - sg : (pos == 2) ? 4 + sg : 11 - sg;

    {
        const int q_lane = tq * 16 + lo;            // this lane's q row
        short8 qf0 = *(const short8*)&lds[LQ_OFF + q_lane * 72 + hi * 8];
        short8 qf1 = *(const short8*)&lds[LQ_OFF + q_lane * 72 + hi * 8 + 32];

        f32x4 acc_o[4];                             // O^T: acc_o[n][r] = O[h=n*16+hi*4+r][q=lo]
        #pragma unroll
        for (int n = 0; n < 4; ++n) acc_o[n] = (f32x4){0.f, 0.f, 0.f, 0.f};
        float Mr = -1e30f, Lr = 0.f;

        const int nsteps = (tq >> 1) + 1;
        for (int s = 0; s < nsteps; ++s) {
            const int kv0 = s * 32;
            f32x4 sb[2];
            sb[0] = (f32x4){0.f, 0.f, 0.f, 0.f};
            sb[1] = (f32x4){0.f, 0.f, 0.f, 0.f};
            __builtin_amdgcn_s_setprio(1);
            #pragma unroll
            for (int n = 0; n < 2; ++n) {
                const unsigned short* kb = &lds[LK_OFF + (kv0 + n * 16 + lo) * 72 + hi * 8];
                short8 kf0 = *(const short8*)kb;
                short8 kf1 = *(const short8*)(kb + 32);
                sb[n] = __builtin_amdgcn_mfma_f32_16x16x32_bf16(kf0, qf0, sb[n], 0, 0, 0);
                sb[n] = __builtin_amdgcn_mfma_f32_16x16x32_bf16(kf1, qf1, sb[n], 0, 0, 0);
            }
            __builtin_amdgcn_s_setprio(0);
            if (s == nsteps - 1) {                  // causal: kv = kv0+n*16+hi*4+r
                #pragma unroll
                for (int n = 0; n < 2; ++n)
                    #pragma unroll
                    for (int r = 0; r < 4; ++r)
                        if (kv0 + n * 16 + hi * 4 + r > q_lane) sb[n][r] = -1e30f;
            }
            float pmax = fmaxf(fmaxf(fmaxf(sb[0][0], sb[0][1]), fmaxf(sb[0][2], sb[0][3])),
                               fmaxf(fmaxf(sb[1][0], sb[1][1]), fmaxf(sb[1][2], sb[1][3])));
            pmax = fmaxf(pmax, __shfl_xor(pmax, 16));
            pmax = fmaxf(pmax, __shfl_xor(pmax, 32));
            float Mn;
            if (__all(pmax - Mr <= 11.5415603f)) {  // T13 defer-max (8*log2e)
                Mn = Mr;
            } else {
                Mn = fmaxf(Mr, pmax);
                const float fr = exp2_hw(Mr - Mn);
                Mr = Mn;
                Lr *= fr;
                #pragma unroll
                for (int n = 0; n < 4; ++n) {
                    acc_o[n][0] *= fr; acc_o[n][1] *= fr;
                    acc_o[n][2] *= fr; acc_o[n][3] *= fr;
                }
            }
            float p0 = exp2_hw(sb[0][0] - Mn), p1 = exp2_hw(sb[0][1] - Mn);
            float p2 = exp2_hw(sb[0][2] - Mn), p3 = exp2_hw(sb[0][3] - Mn);
            float p4 = exp2_hw(sb[1][0] - Mn), p5 = exp2_hw(sb[1][1] - Mn);
            float p6 = exp2_hw(sb[1][2] - Mn), p7 = exp2_hw(sb[1][3] - Mn);
            float ls = ((p0 + p1) + (p2 + p3)) + ((p4 + p5) + (p6 + p7));
            ls += __shfl_xor(ls, 16);
            ls += __shfl_xor(ls, 32);
            Lr += ls;
            // T12: P -> PV B-frag entirely in registers (validated r10)
            unsigned Ap, Bp, Cp, Dp;
            asm("v_cvt_pk_bf16_f32 %0, %1, %2" : "=v"(Ap) : "v"(p0), "v"(p1));
            asm("v_cvt_pk_bf16_f32 %0, %1, %2" : "=v"(Bp) : "v"(p2), "v"(p3));
            asm("v_cvt_pk_bf16_f32 %0, %1, %2" : "=v"(Cp) : "v"(p4), "v"(p5));
            asm("v_cvt_pk_bf16_f32 %0, %1, %2" : "=v"(Dp) : "v"(p6), "v"(p7));
            asm("v_permlane32_swap_b32 %0, %1" : "+v"(Ap), "+v"(Cp));
            asm("v_permlane16_swap_b32 %0, %1" : "+v"(Ap), "+v"(Cp));
            asm("v_permlane32_swap_b32 %0, %1" : "+v"(Bp), "+v"(Dp));
            asm("v_permlane16_swap_b32 %0, %1" : "+v"(Bp), "+v"(Dp));
            uint4 pfu = { Ap, Bp, Cp, Dp };
            short8 pf = *(short8*)&pfu;
            __builtin_amdgcn_s_setprio(1);
            #pragma unroll
            for (int n = 0; n < 4; ++n) {
                short8 vf = *(const short8*)&lds[LV_OFF + (n * 16 + lo) * 264 + kv0 + hi * 8];
                acc_o[n] = __builtin_amdgcn_mfma_f32_16x16x32_bf16(vf, pf, acc_o[n], 0, 0, 0);
            }
            __builtin_amdgcn_s_setprio(0);
        }
        const float inv = 1.0f / Lr;
        float* op = out + ((size_t)(b * 256 + q_lane)) * HS_;
        #pragma unroll
        for (int n = 0; n < 4; ++n)
            #pragma unroll
            for (int r = 0; r < 4; ++r)
                __builtin_nontemporal_store(acc_o[n][r] * inv, op + n * 16 + hi * 4 + r);
    }
}

// ---------- launch ----------
extern "C" void kernel_launch(void* const* d_in, const int* in_sizes, int n_in,
                              void* d_out, int out_size, void* d_ws, size_t ws_size,
                              hipStream_t stream) {
    const float* X  = (const float*)d_in[0];
    const float* Wq = (const float*)d_in[1];
    const float* Wk = (const float*)d_in[2];
    const float* Wv = (const float*)d_in[3];
    float* out = (float*)d_out;

    unsigned short* Wfrag = (unsigned short*)d_ws;   // 12*4*3*64*8 u16 = 144 KB

    prep_wfrag<<<36, 256, 0, stream>>>(Wq, Wk, Wv, Wfrag);
    head_fused<<<B_, 1024, 0, stream>>>(X, Wfrag, out);
}

// Round 17
// 35.328 us; speedup vs baseline: 1.2281x; 1.2281x over previous
//
#include <hip/hip_runtime.h>
#include <hip/hip_bf16.h>

#define B_  256
#define T_  256
#define C_  384
#define HS_ 64
#define BT_ (B_*T_)

typedef __attribute__((ext_vector_type(8))) short short8;
typedef __attribute__((ext_vector_type(4))) float f32x4;

// ---------- helpers ----------
__device__ __forceinline__ unsigned short f2bf(float f) {
    unsigned u = __float_as_uint(f);
    u += 0x7FFFu + ((u >> 16) & 1u);   // round-to-nearest-even
    return (unsigned short)(u >> 16);
}
// 2^x via v_exp_f32 (gfx950 hardware exp is base-2)
__device__ __forceinline__ float exp2_hw(float x) {
    return __builtin_amdgcn_exp2f(x);
}

// Raw barrier that does NOT drain vmcnt (unlike __syncthreads): LDS ordering
// via lgkmcnt(0); sched_barrier pins the fence (guide rule #18 / m201 template).
__device__ __forceinline__ void lds_barrier() {
    asm volatile("s_waitcnt lgkmcnt(0)" ::: "memory");
    __builtin_amdgcn_s_barrier();
    __builtin_amdgcn_sched_barrier(0);
}

// ---------- kernel 0: W -> MFMA-fragment-ordered bf16 ----------
// Wfrag[s][wn][f][lane] (short8): element col n = wn*48+f*16+(lane&15),
// k = s*32+(lane>>4)*8+j.
// Q columns pre-scaled by 384^-0.5 * log2(e)  (softmax runs in exp2 domain).
__global__ __launch_bounds__(256) void prep_wfrag(
    const float* __restrict__ Wq, const float* __restrict__ Wk,
    const float* __restrict__ Wv, unsigned short* __restrict__ Wfrag)
{
    const int tid  = blockIdx.x * 256 + threadIdx.x;   // 9216 threads
    const int lane = tid & 63;
    const int q    = tid >> 6;
    const int f    = q % 3;
    const int q2   = q / 3;
    const int wn   = q2 & 3;
    const int s    = q2 >> 2;

    const int n     = wn * 48 + f * 16 + (lane & 15);
    const int kbase = s * 32 + (lane >> 4) * 8;
    const float* src = (n < 64) ? Wq : (n < 128) ? Wk : Wv;
    const int c      = n & 63;
    const float scale = (n < 64) ? 0.07362222f : 1.0f;   // 384^-0.5 * log2(e)

    short8 out;
    #pragma unroll
    for (int j = 0; j < 8; ++j)
        out[j] = (short)f2bf(src[(size_t)(kbase + j) * HS_ + c] * scale);
    *(short8*)&Wfrag[(size_t)tid * 8] = out;
}

// ---------- fused kernel: QKV projection + causal flash attention ----------
// One block per batch, 1024 thr = 16 waves (4 waves/SIMD).
// GEMM: M=256 x N=192 x K=384; wave (wm,wn) owns rows wm*64..+64, cols wn*48..+48.
// X staging depth-2 pipelined (plain loads; nt regressed in r16). W fragments
// from L2 (fragment-ordered, coalesced). Raw s_barrier per step (no vmcnt drain).
// Attention (swapped-MFMA): QK^T = mfma(K,Q); in-lane exp2-domain softmax +
// defer-max (T13); P -> PV B-frag in registers via cvt_pk + permlane (T12);
// PV = mfma(V,P) -> O^T.
// LDS map (u16 units):
//   Qs  [256][72]  @ 0       (18432)
//   Ks  [256][72]  @ 18432   (18432)
//   Vts [64][280]  @ 36864   (17920)   V transposed [h][tok]; stride 280
//                                      (140 dw = 12 banks mod 32 -> 2-way max)
//   Xs  [2][256][40] @ 54784 (20480)   GEMM staging (dead in phase 2)
// total 75264 u16 = 150528 B
#define LQ_OFF 0
#define LK_OFF 18432
#define LV_OFF 36864
#define LVS    280
#define LX_OFF 54784

__global__ __launch_bounds__(1024, 4) void head_fused(
    const float* __restrict__ X, const unsigned short* __restrict__ Wfrag,
    float* __restrict__ out)
{
    __shared__ unsigned short lds[75264];
    const int t    = threadIdx.x;
    const int w    = t >> 6;        // 0..15
    const int lane = t & 63;
    const int lo   = lane & 15;
    const int hi   = lane >> 4;
    const int b    = blockIdx.x;
    const int wm   = w >> 2, wn = w & 3;

    const float* Xb = X + (size_t)b * T_ * C_;
    const short8* Wf = (const short8*)Wfrag;

    // ================= phase 1: QKV GEMM =================
    const int srow  = t >> 2;       // 0..255
    const int squad = t & 3;        // 8-float chunk of the 32-k slice

    auto stage_load = [&](int k0, float4* g) {
        const float* p = Xb + (size_t)srow * C_ + k0 + squad * 8;
        g[0] = *(const float4*)(p);
        g[1] = *(const float4*)(p + 4);
    };
    auto stage_write = [&](int buf, const float4* g) {
        unsigned a0, a1, a2, a3;
        asm("v_cvt_pk_bf16_f32 %0, %1, %2" : "=v"(a0) : "v"(g[0].x), "v"(g[0].y));
        asm("v_cvt_pk_bf16_f32 %0, %1, %2" : "=v"(a1) : "v"(g[0].z), "v"(g[0].w));
        asm("v_cvt_pk_bf16_f32 %0, %1, %2" : "=v"(a2) : "v"(g[1].x), "v"(g[1].y));
        asm("v_cvt_pk_bf16_f32 %0, %1, %2" : "=v"(a3) : "v"(g[1].z), "v"(g[1].w));
        uint4 p = { a0, a1, a2, a3 };
        *(uint4*)&lds[LX_OFF + buf * 10240 + srow * 40 + squad * 8] = p;
    };
    auto load_w = [&](int s, short8* wf) {      // coalesced fragment loads
        const short8* base = Wf + ((size_t)(s * 4 + wn) * 3) * 64 + lane;
        #pragma unroll
        for (int f = 0; f < 3; ++f)
            wf[f] = base[f * 64];
    };

    float4 gx[2][2];                 // depth-2 X pipeline
    short8 wfr[2][3];
    stage_load(0, gx[0]);
    load_w(0, wfr[0]);
    stage_load(32, gx[1]);
    stage_write(0, gx[0]);
    lds_barrier();

    f32x4 acc[4][3];
    #pragma unroll
    for (int m = 0; m < 4; ++m)
        #pragma unroll
        for (int f = 0; f < 3; ++f)
            acc[m][f] = (f32x4){0.f, 0.f, 0.f, 0.f};

    #pragma unroll 2
    for (int s = 0; s < 12; ++s) {
        const int cur = s & 1;
        if (s < 10) stage_load((s + 2) * 32, gx[cur]);     // issue 2 ahead
        if (s < 11) load_w(s + 1, wfr[cur ^ 1]);           // W 1 ahead
        if (s < 11) stage_write(cur ^ 1, gx[cur ^ 1]);     // write s+1 (arrived)

        short8 af[4];                               // A-frag: row=lo, k=hi*8+j
        #pragma unroll
        for (int m = 0; m < 4; ++m)
            af[m] = *(const short8*)&lds[LX_OFF + cur * 10240 + (wm * 64 + m * 16 + lo) * 40 + hi * 8];
        #pragma unroll
        for (int m = 0; m < 4; ++m)
            #pragma unroll
            for (int f = 0; f < 3; ++f)
                acc[m][f] = __builtin_amdgcn_mfma_f32_16x16x32_bf16(af[m], wfr[cur][f], acc[m][f], 0, 0, 0);
        lds_barrier();
    }

    // epilogue: D col = wn*48+f*16+lo, row = wm*64+m*16+hi*4+r  -> LDS Q/K/Vt
    #pragma unroll
    for (int m = 0; m < 4; ++m) {
        const int rowb = wm * 64 + m * 16 + hi * 4;
        #pragma unroll
        for (int f = 0; f < 3; ++f) {
            const int base = wn * 48 + f * 16;      // frag fully inside one of Q/K/V
            if (base < 64) {
                #pragma unroll
                for (int r = 0; r < 4; ++r)
                    lds[LQ_OFF + (rowb + r) * 72 + base + lo] = f2bf(acc[m][f][r]);
            } else if (base < 128) {
                #pragma unroll
                for (int r = 0; r < 4; ++r)
                    lds[LK_OFF + (rowb + r) * 72 + (base - 64) + lo] = f2bf(acc[m][f][r]);
            } else {
                unsigned e0, e1;
                asm("v_cvt_pk_bf16_f32 %0, %1, %2" : "=v"(e0) : "v"(acc[m][f][0]), "v"(acc[m][f][1]));
                asm("v_cvt_pk_bf16_f32 %0, %1, %2" : "=v"(e1) : "v"(acc[m][f][2]), "v"(acc[m][f][3]));
                uint2 pk = { e0, e1 };
                *(uint2*)&lds[LV_OFF + (base - 128 + lo) * LVS + rowb] = pk;
            }
        }
    }
    lds_barrier();

    // ======== phase 2: causal flash attention (swapped MFMA, reg-only P) ========
    // Scores in log2 domain (log2e folded into Q): p = exp2(s - M).
    // SIMD-balanced tile assignment: SIMD g gets {g, 15-g, 4+g, 11-g} = 18 steps
    const int sg  = w & 3, pos = w >> 2;
    const int tq  = (pos == 0) ? sg : (pos == 1) ? 15 - sg : (pos == 2) ? 4 + sg : 11 - sg;

    {
        const int q_lane = tq * 16 + lo;            // this lane's q row
        short8 qf0 = *(const short8*)&lds[LQ_OFF + q_lane * 72 + hi * 8];
        short8 qf1 = *(const short8*)&lds[LQ_OFF + q_lane * 72 + hi * 8 + 32];

        f32x4 acc_o[4];                             // O^T: acc_o[n][r] = O[h=n*16+hi*4+r][q=lo]
        #pragma unroll
        for (int n = 0; n < 4; ++n) acc_o[n] = (f32x4){0.f, 0.f, 0.f, 0.f};
        float Mr = -1e30f, Lr = 0.f;

        const int nsteps = (tq >> 1) + 1;
        for (int s = 0; s < nsteps; ++s) {
            const int kv0 = s * 32;
            f32x4 sb[2];
            sb[0] = (f32x4){0.f, 0.f, 0.f, 0.f};
            sb[1] = (f32x4){0.f, 0.f, 0.f, 0.f};
            __builtin_amdgcn_s_setprio(1);
            #pragma unroll
            for (int n = 0; n < 2; ++n) {
                const unsigned short* kb = &lds[LK_OFF + (kv0 + n * 16 + lo) * 72 + hi * 8];
                short8 kf0 = *(const short8*)kb;
                short8 kf1 = *(const short8*)(kb + 32);
                sb[n] = __builtin_amdgcn_mfma_f32_16x16x32_bf16(kf0, qf0, sb[n], 0, 0, 0);
                sb[n] = __builtin_amdgcn_mfma_f32_16x16x32_bf16(kf1, qf1, sb[n], 0, 0, 0);
            }
            __builtin_amdgcn_s_setprio(0);
            if (s == nsteps - 1) {                  // causal: kv = kv0+n*16+hi*4+r
                #pragma unroll
                for (int n = 0; n < 2; ++n)
                    #pragma unroll
                    for (int r = 0; r < 4; ++r)
                        if (kv0 + n * 16 + hi * 4 + r > q_lane) sb[n][r] = -1e30f;
            }
            float pmax = fmaxf(fmaxf(fmaxf(sb[0][0], sb[0][1]), fmaxf(sb[0][2], sb[0][3])),
                               fmaxf(fmaxf(sb[1][0], sb[1][1]), fmaxf(sb[1][2], sb[1][3])));
            pmax = fmaxf(pmax, __shfl_xor(pmax, 16));
            pmax = fmaxf(pmax, __shfl_xor(pmax, 32));
            float Mn;
            if (__all(pmax - Mr <= 11.5415603f)) {  // T13 defer-max (8*log2e)
                Mn = Mr;
            } else {
                Mn = fmaxf(Mr, pmax);
                const float fr = exp2_hw(Mr - Mn);
                Mr = Mn;
                Lr *= fr;
                #pragma unroll
                for (int n = 0; n < 4; ++n) {
                    acc_o[n][0] *= fr; acc_o[n][1] *= fr;
                    acc_o[n][2] *= fr; acc_o[n][3] *= fr;
                }
            }
            float p0 = exp2_hw(sb[0][0] - Mn), p1 = exp2_hw(sb[0][1] - Mn);
            float p2 = exp2_hw(sb[0][2] - Mn), p3 = exp2_hw(sb[0][3] - Mn);
            float p4 = exp2_hw(sb[1][0] - Mn), p5 = exp2_hw(sb[1][1] - Mn);
            float p6 = exp2_hw(sb[1][2] - Mn), p7 = exp2_hw(sb[1][3] - Mn);
            float ls = ((p0 + p1) + (p2 + p3)) + ((p4 + p5) + (p6 + p7));
            ls += __shfl_xor(ls, 16);
            ls += __shfl_xor(ls, 32);
            Lr += ls;
            // T12: P -> PV B-frag entirely in registers (validated r10)
            unsigned Ap, Bp, Cp, Dp;
            asm("v_cvt_pk_bf16_f32 %0, %1, %2" : "=v"(Ap) : "v"(p0), "v"(p1));
            asm("v_cvt_pk_bf16_f32 %0, %1, %2" : "=v"(Bp) : "v"(p2), "v"(p3));
            asm("v_cvt_pk_bf16_f32 %0, %1, %2" : "=v"(Cp) : "v"(p4), "v"(p5));
            asm("v_cvt_pk_bf16_f32 %0, %1, %2" : "=v"(Dp) : "v"(p6), "v"(p7));
            asm("v_permlane32_swap_b32 %0, %1" : "+v"(Ap), "+v"(Cp));
            asm("v_permlane16_swap_b32 %0, %1" : "+v"(Ap), "+v"(Cp));
            asm("v_permlane32_swap_b32 %0, %1" : "+v"(Bp), "+v"(Dp));
            asm("v_permlane16_swap_b32 %0, %1" : "+v"(Bp), "+v"(Dp));
            uint4 pfu = { Ap, Bp, Cp, Dp };
            short8 pf = *(short8*)&pfu;
            __builtin_amdgcn_s_setprio(1);
            #pragma unroll
            for (int n = 0; n < 4; ++n) {
                short8 vf = *(const short8*)&lds[LV_OFF + (n * 16 + lo) * LVS + kv0 + hi * 8];
                acc_o[n] = __builtin_amdgcn_mfma_f32_16x16x32_bf16(vf, pf, acc_o[n], 0, 0, 0);
            }
            __builtin_amdgcn_s_setprio(0);
        }
        const float inv = 1.0f / Lr;
        float* op = out + ((size_t)(b * 256 + q_lane)) * HS_;
        #pragma unroll
        for (int n = 0; n < 4; ++n)
            #pragma unroll
            for (int r = 0; r < 4; ++r)
                op[n * 16 + hi * 4 + r] = acc_o[n][r] * inv;
    }
}

// ---------- launch ----------
extern "C" void kernel_launch(void* const* d_in, const int* in_sizes, int n_in,
                              void* d_out, int out_size, void* d_ws, size_t ws_size,
                              hipStream_t stream) {
    const float* X  = (const float*)d_in[0];
    const float* Wq = (const float*)d_in[1];
    const float* Wk = (const float*)d_in[2];
    const float* Wv = (const float*)d_in[3];
    float* out = (float*)d_out;

    unsigned short* Wfrag = (unsigned short*)d_ws;   // 12*4*3*64*8 u16 = 144 KB

    prep_wfrag<<<36, 256, 0, stream>>>(Wq, Wk, Wv, Wfrag);
    head_fused<<<B_, 1024, 0, stream>>>(X, Wfrag, out);
}